// Round 3
// baseline (563.579 us; speedup 1.0000x reference)
//
#include <hip/hip_runtime.h>

typedef unsigned short u16;
typedef __attribute__((ext_vector_type(8))) short bf16x8;
typedef __attribute__((ext_vector_type(4))) float f32x4;

#define L_SEQ 16384
#define NHEAD 16
#define CDIM  512
#define SCALE 0.17677669529663689f

#define LC    2048                         // interior rows per chunk per b
#define LCH   2176                         // stored rows per chunk per b (17 x 128)
#define QKV_PLANE (2 * NHEAD * LCH * 32)   // 2,228,224 elements per {q,k,v} plane

__device__ __forceinline__ float bf2f(u16 v) {
    union { unsigned int u; float f; } x; x.u = ((unsigned int)v) << 16; return x.f;
}
__device__ __forceinline__ u16 f2bf(float f) {
    union { unsigned int u; float f; } x; x.f = f;
    unsigned int r = x.u + 0x7fff + ((x.u >> 16) & 1);
    return (u16)(r >> 16);
}

// ---- dtype detector: f32 buffers have junk low-mantissa u16s whose bf16-exponent
// field is all-ones with p=1/256; finite bf16 data never matches. 8192 samples.
__global__ void detect_dtype_kernel(const u16* __restrict__ x, int* __restrict__ flag) {
    __shared__ int cnt;
    if (threadIdx.x == 0) cnt = 0;
    __syncthreads();
    int c = 0;
    for (int k = 0; k < 32; k++) {
        u16 v = x[2 * (threadIdx.x + 256 * k)];
        if ((v & 0x7F80) == 0x7F80) c++;
    }
    atomicAdd(&cnt, c);
    __syncthreads();
    if (threadIdx.x == 0) *flag = (cnt > 0) ? 1 : 0;
}

// ---- generic small converter (weights / biases / rpb) -> bf16
__global__ void convert_small_kernel(const void* __restrict__ src, u16* __restrict__ dst,
                                     int n, const int* __restrict__ flag) {
    const int f = *flag;
    for (int i = blockIdx.x * blockDim.x + threadIdx.x; i < n; i += gridDim.x * blockDim.x)
        dst[i] = f ? f2bf(((const float*)src)[i]) : ((const u16*)src)[i];
}

// ---- x chunk converter: rows [b*L + base_c, +LCH) per b -> xc[(b*LCH + r)*512 + col]
__global__ __launch_bounds__(256)
void convert_x_kernel(const void* __restrict__ src, u16* __restrict__ dst,
                      int base_c, const int* __restrict__ flag) {
    const int f   = *flag;
    const int i0  = (blockIdx.x * 256 + threadIdx.x) * 8;   // [0, 2*LCH*512)
    const int lr2 = i0 >> 9;
    const int col = i0 & 511;
    const int b   = (lr2 >= LCH) ? 1 : 0;
    const int r   = lr2 - b * LCH;
    const size_t s = (size_t)(b * L_SEQ + base_c + r) * 512 + col;
    if (f) {
        const float* sf = (const float*)src + s;
        union { u16 o[8]; uint4 v; } pk;
        #pragma unroll
        for (int j = 0; j < 8; j++) pk.o[j] = f2bf(sf[j]);
        *(uint4*)(dst + i0) = pk.v;
    } else {
        *(uint4*)(dst + i0) = *(const uint4*)((const u16*)src + s);
    }
}

// ---- conservative GEMM core: 128x128 tile, BK=32, vector-load -> LDS store ----
// A rows AROW0.., W rows N0.., both row-major bf16 with K contiguous. C = A @ W^T.
#define GEMM_CORE(A_PTR, W_PTR, KD, AROW0, N0)                                             \
    __shared__ u16 As[128 * 32];                                                           \
    __shared__ u16 Ws[128 * 32];                                                           \
    const int tid  = threadIdx.x;                                                          \
    const int wave = tid >> 6;                                                             \
    const int lane = tid & 63;                                                             \
    const int quad = lane >> 4;                                                            \
    const int r16  = lane & 15;                                                            \
    const int wm   = (wave >> 1) << 6;                                                     \
    const int wn   = (wave & 1) << 6;                                                      \
    f32x4 acc[4][4];                                                                       \
    _Pragma("unroll")                                                                      \
    for (int i = 0; i < 4; i++)                                                            \
        _Pragma("unroll")                                                                  \
        for (int j = 0; j < 4; j++) acc[i][j] = (f32x4){0.f, 0.f, 0.f, 0.f};               \
    const int srow = tid >> 2;                                                             \
    const int scol = (tid & 3) << 3;                                                      \
    const u16* gA = (A_PTR) + (size_t)((AROW0) + srow) * (KD) + scol;                      \
    const u16* gW = (W_PTR) + (size_t)((N0) + srow) * (KD) + scol;                         \
    for (int kt = 0; kt < (KD); kt += 32) {                                                \
        bf16x8 a0 = *(const bf16x8*)(gA + kt);                                             \
        bf16x8 a1 = *(const bf16x8*)(gA + (size_t)64 * (KD) + kt);                         \
        bf16x8 w0 = *(const bf16x8*)(gW + kt);                                             \
        bf16x8 w1 = *(const bf16x8*)(gW + (size_t)64 * (KD) + kt);                         \
        *(bf16x8*)&As[srow * 32 + scol]        = a0;                                       \
        *(bf16x8*)&As[(srow + 64) * 32 + scol] = a1;                                       \
        *(bf16x8*)&Ws[srow * 32 + scol]        = w0;                                       \
        *(bf16x8*)&Ws[(srow + 64) * 32 + scol] = w1;                                       \
        __syncthreads();                                                                   \
        bf16x8 af[4], bfr[4];                                                              \
        _Pragma("unroll")                                                                  \
        for (int mi = 0; mi < 4; mi++)                                                     \
            af[mi] = *(const bf16x8*)&As[(wm + mi * 16 + r16) * 32 + quad * 8];            \
        _Pragma("unroll")                                                                  \
        for (int ni = 0; ni < 4; ni++)                                                     \
            bfr[ni] = *(const bf16x8*)&Ws[(wn + ni * 16 + r16) * 32 + quad * 8];           \
        _Pragma("unroll")                                                                  \
        for (int mi = 0; mi < 4; mi++)                                                     \
            _Pragma("unroll")                                                              \
            for (int ni = 0; ni < 4; ni++)                                                 \
                acc[mi][ni] = __builtin_amdgcn_mfma_f32_16x16x32_bf16(                     \
                    af[mi], bfr[ni], acc[mi][ni], 0, 0, 0);                                \
        __syncthreads();                                                                   \
    }

// ---- QKV GEMM over one chunk: xc[(b*LCH+r), 512] @ qkv_w^T -> planes
// [3][b*16+h][LCH][32], q pre-scaled.
__global__ __launch_bounds__(256)
void gemm_qkv_kernel(const u16* __restrict__ A, const u16* __restrict__ W,
                     const u16* __restrict__ bias, u16* __restrict__ qkv_out)
{
    const int m0l = blockIdx.y << 7;               // [0, LCH)
    const int b   = blockIdx.z;
    const int n0  = blockIdx.x << 7;
    GEMM_CORE(A, W, 512, b * LCH + m0l, n0)
    #pragma unroll
    for (int ni = 0; ni < 4; ni++) {
        const int col   = n0 + wn + ni * 16 + r16;
        const int which = col >> 9;
        const int rem   = col & 511;
        const int h     = rem >> 5;
        const int d     = rem & 31;
        const float bv  = bf2f(bias[col]);
        const float scl = (which == 0) ? SCALE : 1.0f;
        u16* outb = qkv_out + (size_t)which * QKV_PLANE;
        #pragma unroll
        for (int mi = 0; mi < 4; mi++) {
            #pragma unroll
            for (int r = 0; r < 4; r++) {
                const int rrel = m0l + wm + mi * 16 + quad * 4 + r;   // [0, LCH)
                outb[((size_t)(b * NHEAD + h) * LCH + rrel) * 32 + d] =
                    f2bf((acc[mi][ni][r] + bv) * scl);
            }
        }
    }
}

// ---- attention over one chunk: one 32-lane group per (b,h,lr), lr in [0, LC)
__global__ __launch_bounds__(256)
void attn_kernel(const u16* __restrict__ q, const u16* __restrict__ k,
                 const u16* __restrict__ v, const u16* __restrict__ rpb,
                 u16* __restrict__ outa, int c0, int base_c)
{
    const int grp = (blockIdx.x << 3) + (threadIdx.x >> 5);
    const int d   = threadIdx.x & 31;
    const int lr  = grp & (LC - 1);
    const int bh  = grp >> 11;                      // b*16 + h  (LC = 2^11)
    const int h   = bh & 15;
    const int l   = c0 + lr;
    const size_t base = (size_t)bh * LCH * 32;

    const float qv = bf2f(q[base + (size_t)(l - base_c) * 32 + d]);
    int ni = l - 3;
    if (ni < 0) ni = 0;
    if (ni > L_SEQ - 7) ni = L_SEQ - 7;
    const int rn = ni - base_c;                     // in [0, LCH-7]

    float logit[7];
    #pragma unroll
    for (int j = 0; j < 7; j++) {
        float p = qv * bf2f(k[base + (size_t)(rn + j) * 32 + d]);
        #pragma unroll
        for (int m = 16; m >= 1; m >>= 1) p += __shfl_xor(p, m, 64);
        logit[j] = p + bf2f(rpb[h * 13 + (ni + j - l + 6)]);
    }
    float mx = logit[0];
    #pragma unroll
    for (int j = 1; j < 7; j++) mx = fmaxf(mx, logit[j]);
    float s = 0.f, w[7];
    #pragma unroll
    for (int j = 0; j < 7; j++) { w[j] = __expf(logit[j] - mx); s += w[j]; }
    const float inv = 1.0f / s;
    float o = 0.f;
    #pragma unroll
    for (int j = 0; j < 7; j++) o += w[j] * bf2f(v[base + (size_t)(rn + j) * 32 + d]);

    outa[((size_t)((bh >> 4) * LC + lr) << 9) + (h << 5) + d] = f2bf(o * inv);
}

// ---- proj GEMM over one chunk: wsa[b*LC+lr, 512] @ proj_w^T -> out rows b*L+c0+lr
__global__ __launch_bounds__(256)
void gemm_proj_kernel(const u16* __restrict__ A, const u16* __restrict__ W,
                      const u16* __restrict__ bias, void* __restrict__ out,
                      int c0, const int* __restrict__ flag)
{
    const int m0l = blockIdx.y << 7;               // [0, LC)
    const int b   = blockIdx.z;
    const int n0  = blockIdx.x << 7;
    GEMM_CORE(A, W, 512, b * LC + m0l, n0)
    const int f = *flag;
    #pragma unroll
    for (int ni = 0; ni < 4; ni++) {
        const int col  = n0 + wn + ni * 16 + r16;
        const float bv = bf2f(bias[col]);
        #pragma unroll
        for (int mi = 0; mi < 4; mi++) {
            #pragma unroll
            for (int r = 0; r < 4; r++) {
                const int lr = m0l + wm + mi * 16 + quad * 4 + r;   // [0, LC)
                const size_t idx = (size_t)(b * L_SEQ + c0 + lr) * CDIM + col;
                const float val = acc[mi][ni][r] + bv;
                if (f) ((float*)out)[idx] = val;
                else   ((u16*)out)[idx]   = f2bf(val);
            }
        }
    }
}

extern "C" void kernel_launch(void* const* d_in, const int* in_sizes, int n_in,
                              void* d_out, int out_size, void* d_ws, size_t ws_size,
                              hipStream_t stream) {
    const void* x      = d_in[0];
    const void* qkv_w  = d_in[1];
    const void* qkv_b  = d_in[2];
    const void* rpb    = d_in[3];
    const void* proj_w = d_in[4];
    const void* proj_b = d_in[5];

    u16* ws    = (u16*)d_ws;
    int* flag  = (int*)ws;                          // 16 u16 reserved
    u16* xc    = ws + 16;                           // 2*LCH*512 = 2,228,224
    u16* wqkv  = xc + 2 * LCH * 512;                // 786,432
    u16* wproj = wqkv + 1536 * 512;                 // 262,144
    u16* bqkv  = wproj + 512 * 512;                 // 1,536
    u16* bproj = bqkv + 1536;                       // 512
    u16* rpbc  = bproj + 512;                       // 256 (208 used)
    u16* qkv   = rpbc + 256;                        // 3 * QKV_PLANE
    u16* wsa   = qkv + (size_t)3 * QKV_PLANE;       // 2*LC*512 = 2,097,152
    // total ~= 12.06 M u16 ~= 24.1 MB

    detect_dtype_kernel<<<1, 256, 0, stream>>>((const u16*)x, flag);
    convert_small_kernel<<<768, 256, 0, stream>>>(qkv_w, wqkv, 1536 * 512, flag);
    convert_small_kernel<<<256, 256, 0, stream>>>(proj_w, wproj, 512 * 512, flag);
    convert_small_kernel<<<2, 256, 0, stream>>>(qkv_b, bqkv, 1536, flag);
    convert_small_kernel<<<1, 256, 0, stream>>>(proj_b, bproj, 512, flag);
    convert_small_kernel<<<1, 256, 0, stream>>>(rpb, rpbc, 208, flag);

    const int c0s[8]   = {0, 2048, 4096, 6144, 8192, 10240, 12288, 14336};
    const int bases[8] = {0, 1984, 4032, 6080, 8128, 10176, 12224, 14208};

    for (int c = 0; c < 8; c++) {
        convert_x_kernel<<<1088, 256, 0, stream>>>(x, xc, bases[c], flag);
        gemm_qkv_kernel<<<dim3(12, 17, 2), 256, 0, stream>>>(xc, wqkv, bqkv, qkv);
        attn_kernel<<<dim3(8192), 256, 0, stream>>>(
            qkv, qkv + QKV_PLANE, qkv + (size_t)2 * QKV_PLANE, rpbc,
            wsa, c0s[c], bases[c]);
        gemm_proj_kernel<<<dim3(4, 16, 2), 256, 0, stream>>>(
            wsa, wproj, bproj, d_out, c0s[c], flag);
    }
}

// Round 4
// 338.580 us; speedup vs baseline: 1.6645x; 1.6645x over previous
//
#include <hip/hip_runtime.h>

typedef unsigned short u16;
typedef unsigned int   u32;
typedef __attribute__((ext_vector_type(8))) short bf16x8;
typedef __attribute__((ext_vector_type(4))) float f32x4;

#define L_SEQ 16384
#define NHEAD 16
#define CDIM  512
#define SCALE 0.17677669529663689f

__device__ __forceinline__ float bf2f(u16 v) {
    union { u32 u; float f; } x; x.u = ((u32)v) << 16; return x.f;
}
__device__ __forceinline__ u16 f2bf(float f) {
    union { u32 u; float f; } x; x.f = f;
    u32 r = x.u + 0x7fff + ((x.u >> 16) & 1);
    return (u16)(r >> 16);
}

// ---- dtype detector: f32 junk low-halves hit bf16-exponent-all-ones w/ p=1/256.
__global__ void detect_dtype_kernel(const u16* __restrict__ x, int* __restrict__ flag) {
    __shared__ int cnt;
    if (threadIdx.x == 0) cnt = 0;
    __syncthreads();
    int c = 0;
    for (int k = 0; k < 32; k++) {
        u16 v = x[2 * (threadIdx.x + 256 * k)];
        if ((v & 0x7F80) == 0x7F80) c++;
    }
    atomicAdd(&cnt, c);
    __syncthreads();
    if (threadIdx.x == 0) *flag = (cnt > 0) ? 1 : 0;
}

// ---- all weights/biases/rpb -> one contiguous bf16 segment (5 sub-ranges)
__global__ __launch_bounds__(256)
void convert_weights_kernel(const void* __restrict__ qkv_w, const void* __restrict__ proj_w,
                            const void* __restrict__ qkv_b, const void* __restrict__ proj_b,
                            const void* __restrict__ rpb, u16* __restrict__ dst,
                            const int* __restrict__ flag) {
    const int f = *flag;
    for (int i = blockIdx.x * 256 + threadIdx.x; i < 1050832; i += gridDim.x * 256) {
        const void* src; int off;
        if (i < 786432)       { src = qkv_w;  off = i; }
        else if (i < 1048576) { src = proj_w; off = i - 786432; }
        else if (i < 1050112) { src = qkv_b;  off = i - 1048576; }
        else if (i < 1050624) { src = proj_b; off = i - 1050112; }
        else                  { src = rpb;    off = i - 1050624; }
        dst[i] = f ? f2bf(((const float*)src)[off]) : ((const u16*)src)[off];
    }
}

// ---- x rows [b*L+base_c, +lch) per b -> xc[(b*lch + r)*512 + col] bf16
__global__ __launch_bounds__(256)
void convert_x_kernel(const void* __restrict__ src, u16* __restrict__ dst,
                      int base_c, int lch, const int* __restrict__ flag) {
    const int f  = *flag;
    const int i0 = (blockIdx.x * 256 + threadIdx.x) * 8;     // [0, 2*lch*512)
    const int r  = i0 >> 9;
    const int b  = (r >= lch) ? 1 : 0;
    const size_t s = (size_t)(b * L_SEQ + base_c + (r - b * lch)) * 512 + (i0 & 511);
    if (f) {
        const float* sf = (const float*)src + s;
        union { u16 o[8]; uint4 v; } pk;
        #pragma unroll
        for (int j = 0; j < 8; j++) pk.o[j] = f2bf(sf[j]);
        *(uint4*)(dst + i0) = pk.v;
    } else {
        *(uint4*)(dst + i0) = *(const uint4*)((const u16*)src + s);
    }
}

// ---- m97-structure GEMM core: 128x128 tile, BK=32, global_load_lds width-16 ----
// A rows AROW0.., W rows N0.. (row-major bf16, K contiguous). C = A @ W^T.
#define GEMM_CORE(A_PTR, W_PTR, KD, AROW0, N0)                                             \
    __shared__ u16 As[128 * 32];                                                           \
    __shared__ u16 Ws[128 * 32];                                                           \
    const int tid  = threadIdx.x;                                                          \
    const int wave = tid >> 6;                                                             \
    const int lane = tid & 63;                                                             \
    const int quad = lane >> 4;                                                            \
    const int r16  = lane & 15;                                                            \
    const int wm   = (wave >> 1) << 6;                                                     \
    const int wn   = (wave & 1) << 6;                                                      \
    f32x4 acc[4][4];                                                                       \
    _Pragma("unroll")                                                                      \
    for (int i = 0; i < 4; i++)                                                            \
        _Pragma("unroll")                                                                  \
        for (int j = 0; j < 4; j++) acc[i][j] = (f32x4){0.f, 0.f, 0.f, 0.f};               \
    const int srow = lane >> 2;                                                            \
    const int scol = (lane & 3) << 3;                                                      \
    u16* asb0 = As + wave * 512;                                                           \
    u16* asb1 = As + 2048 + wave * 512;                                                    \
    u16* wsb0 = Ws + wave * 512;                                                           \
    u16* wsb1 = Ws + 2048 + wave * 512;                                                    \
    const u16* ga = (A_PTR) + (size_t)((AROW0) + wave * 16 + srow) * (KD) + scol;          \
    const u16* gw = (W_PTR) + (size_t)((N0) + wave * 16 + srow) * (KD) + scol;             \
    for (int kt = 0; kt < (KD); kt += 32) {                                                \
        __builtin_amdgcn_global_load_lds(                                                  \
            (const __attribute__((address_space(1))) void*)(ga + kt),                      \
            (__attribute__((address_space(3))) void*)asb0, 16, 0, 0);                      \
        __builtin_amdgcn_global_load_lds(                                                  \
            (const __attribute__((address_space(1))) void*)(ga + (size_t)64 * (KD) + kt),  \
            (__attribute__((address_space(3))) void*)asb1, 16, 0, 0);                      \
        __builtin_amdgcn_global_load_lds(                                                  \
            (const __attribute__((address_space(1))) void*)(gw + kt),                      \
            (__attribute__((address_space(3))) void*)wsb0, 16, 0, 0);                      \
        __builtin_amdgcn_global_load_lds(                                                  \
            (const __attribute__((address_space(1))) void*)(gw + (size_t)64 * (KD) + kt),  \
            (__attribute__((address_space(3))) void*)wsb1, 16, 0, 0);                      \
        __syncthreads();                                                                   \
        bf16x8 af[4], bfr[4];                                                              \
        _Pragma("unroll")                                                                  \
        for (int mi = 0; mi < 4; mi++)                                                     \
            af[mi] = *(const bf16x8*)&As[(wm + mi * 16 + r16) * 32 + quad * 8];            \
        _Pragma("unroll")                                                                  \
        for (int ni = 0; ni < 4; ni++)                                                     \
            bfr[ni] = *(const bf16x8*)&Ws[(wn + ni * 16 + r16) * 32 + quad * 8];           \
        _Pragma("unroll")                                                                  \
        for (int mi = 0; mi < 4; mi++)                                                     \
            _Pragma("unroll")                                                              \
            for (int ni = 0; ni < 4; ni++)                                                 \
                acc[mi][ni] = __builtin_amdgcn_mfma_f32_16x16x32_bf16(                     \
                    af[mi], bfr[ni], acc[mi][ni], 0, 0, 0);                                \
        __syncthreads();                                                                   \
    }

// ---- QKV GEMM: xc[(b*lch+r),512] @ qkv_w^T -> planes [3][b*16+h][lch][32], q*SCALE
__global__ __launch_bounds__(256)
void gemm_qkv_kernel(const u16* __restrict__ A, const u16* __restrict__ W,
                     const u16* __restrict__ bias, u16* __restrict__ qkv_out, int lch)
{
    const int m0l = blockIdx.y << 7;
    const int b   = blockIdx.z;
    const int n0  = blockIdx.x << 7;
    const size_t plane = (size_t)1024 * lch;       // 2*16*lch*32
    GEMM_CORE(A, W, 512, b * lch + m0l, n0)
    #pragma unroll
    for (int ni = 0; ni < 4; ni++) {
        const int col   = n0 + wn + ni * 16 + r16;
        const int which = col >> 9;
        const int rem   = col & 511;
        const int h     = rem >> 5;
        const int d     = rem & 31;
        const float bv  = bf2f(bias[col]);
        const float scl = (which == 0) ? SCALE : 1.0f;
        u16* outb = qkv_out + (size_t)which * plane;
        #pragma unroll
        for (int mi = 0; mi < 4; mi++) {
            #pragma unroll
            for (int r = 0; r < 4; r++) {
                const int rrel = m0l + wm + mi * 16 + quad * 4 + r;
                outb[((size_t)(b * NHEAD + h) * lch + rrel) * 32 + d] =
                    f2bf((acc[mi][ni][r] + bv) * scl);
            }
        }
    }
}

// ---- attention: 16 lanes per (b,h,l), each lane owns a bf16 pair (d2 = d/2)
__global__ __launch_bounds__(256)
void attn_kernel(const u32* __restrict__ q, const u32* __restrict__ k,
                 const u32* __restrict__ v, const u16* __restrict__ rpb,
                 u32* __restrict__ outa, int c0, int base_c, int lc_shift, int lch)
{
    const int grp = blockIdx.x * 16 + (threadIdx.x >> 4);
    const int d2  = threadIdx.x & 15;
    const int lc_mask = (1 << lc_shift) - 1;
    const int lr  = grp & lc_mask;
    const int bh  = grp >> lc_shift;                // b*16 + h
    const int h   = bh & 15;
    const int l   = c0 + lr;
    const size_t base = (size_t)bh * lch * 16;      // in u32 units

    const u32 qp = q[base + (size_t)(l - base_c) * 16 + d2];
    const float qlo = bf2f((u16)qp), qhi = bf2f((u16)(qp >> 16));
    int ni = l - 3;
    if (ni < 0) ni = 0;
    if (ni > L_SEQ - 7) ni = L_SEQ - 7;
    const int rn = ni - base_c;

    float logit[7];
    #pragma unroll
    for (int j = 0; j < 7; j++) {
        const u32 kp = k[base + (size_t)(rn + j) * 16 + d2];
        float p = qlo * bf2f((u16)kp) + qhi * bf2f((u16)(kp >> 16));
        #pragma unroll
        for (int m = 8; m >= 1; m >>= 1) p += __shfl_xor(p, m, 64);
        logit[j] = p + bf2f(rpb[h * 13 + (ni + j - l + 6)]);
    }
    float mx = logit[0];
    #pragma unroll
    for (int j = 1; j < 7; j++) mx = fmaxf(mx, logit[j]);
    float s = 0.f, w[7];
    #pragma unroll
    for (int j = 0; j < 7; j++) { w[j] = __expf(logit[j] - mx); s += w[j]; }
    const float inv = 1.0f / s;
    float olo = 0.f, ohi = 0.f;
    #pragma unroll
    for (int j = 0; j < 7; j++) {
        const u32 vp = v[base + (size_t)(rn + j) * 16 + d2];
        olo += w[j] * bf2f((u16)vp);
        ohi += w[j] * bf2f((u16)(vp >> 16));
    }
    const u32 pk = (u32)f2bf(olo * inv) | ((u32)f2bf(ohi * inv) << 16);
    outa[((size_t)(((bh >> 4) << lc_shift) + lr)) * 256 + h * 16 + d2] = pk;
}

// ---- proj GEMM: wsa[(b*lc+lr),512] @ proj_w^T -> out rows b*L + c0 + lr
__global__ __launch_bounds__(256)
void gemm_proj_kernel(const u16* __restrict__ A, const u16* __restrict__ W,
                      const u16* __restrict__ bias, void* __restrict__ out,
                      int c0, int lc, const int* __restrict__ flag)
{
    const int m0l = blockIdx.y << 7;
    const int b   = blockIdx.z;
    const int n0  = blockIdx.x << 7;
    GEMM_CORE(A, W, 512, b * lc + m0l, n0)
    const int f = *flag;
    #pragma unroll
    for (int ni = 0; ni < 4; ni++) {
        const int col  = n0 + wn + ni * 16 + r16;
        const float bv = bf2f(bias[col]);
        #pragma unroll
        for (int mi = 0; mi < 4; mi++) {
            #pragma unroll
            for (int r = 0; r < 4; r++) {
                const int lr = m0l + wm + mi * 16 + quad * 4 + r;
                const size_t idx = (size_t)(b * L_SEQ + c0 + lr) * CDIM + col;
                const float val = acc[mi][ni][r] + bv;
                if (f) ((float*)out)[idx] = val;
                else   ((u16*)out)[idx]   = f2bf(val);
            }
        }
    }
}

extern "C" void kernel_launch(void* const* d_in, const int* in_sizes, int n_in,
                              void* d_out, int out_size, void* d_ws, size_t ws_size,
                              hipStream_t stream) {
    const void* x      = d_in[0];
    const void* qkv_w  = d_in[1];
    const void* qkv_b  = d_in[2];
    const void* rpb    = d_in[3];
    const void* proj_w = d_in[4];
    const void* proj_b = d_in[5];

    // ---- chunk config chosen by ws_size (constant across calls -> graph-safe)
    // need(lch, lc) bytes = 2*(16 + 1050880 + 1024*lch + 3072*lch + 1024*lc)
    int nchunk, lch, lc, lc_shift;
    static const int c0sA[1] = {0},                 basesA[1] = {0};
    static const int c0sB[2] = {0, 8192},           basesB[2] = {0, 8064};
    static const int c0sC[8] = {0, 2048, 4096, 6144, 8192, 10240, 12288, 14336};
    static const int basesC[8] = {0, 1984, 4032, 6080, 8128, 10176, 12224, 14208};
    const int* c0s; const int* bases;
    if (ws_size >= (size_t)2 * (16 + 1050880 + (size_t)4096 * 16384 + 1024 * 16384)) {
        nchunk = 1; lch = 16384; lc = 16384; lc_shift = 14; c0s = c0sA; bases = basesA;
    } else if (ws_size >= (size_t)2 * (16 + 1050880 + (size_t)4096 * 8320 + 1024 * 8192)) {
        nchunk = 2; lch = 8320;  lc = 8192;  lc_shift = 13; c0s = c0sB; bases = basesB;
    } else {
        nchunk = 8; lch = 2176;  lc = 2048;  lc_shift = 11; c0s = c0sC; bases = basesC;
    }

    u16* ws    = (u16*)d_ws;
    int* flag  = (int*)ws;                           // 16 u16
    u16* wseg  = ws + 16;                            // 1,050,880 (wqkv|wproj|bqkv|bproj|rpbc)
    u16* wqkv  = wseg;
    u16* wproj = wseg + 786432;
    u16* bqkv  = wseg + 1048576;
    u16* bproj = wseg + 1050112;
    u16* rpbc  = wseg + 1050624;
    u16* xc    = ws + 16 + 1050880;                  // 2*lch*512
    u16* qkv   = xc + (size_t)1024 * lch;            // 3 planes of 1024*lch
    u16* wsa   = qkv + (size_t)3072 * lch;           // 2*lc*512

    detect_dtype_kernel<<<1, 256, 0, stream>>>((const u16*)x, flag);
    convert_weights_kernel<<<2048, 256, 0, stream>>>(qkv_w, proj_w, qkv_b, proj_b,
                                                     rpb, wseg, flag);

    for (int c = 0; c < nchunk; c++) {
        convert_x_kernel<<<lch / 2, 256, 0, stream>>>(x, xc, bases[c], lch, flag);
        gemm_qkv_kernel<<<dim3(12, lch / 128, 2), 256, 0, stream>>>(
            xc, wqkv, bqkv, qkv, lch);
        attn_kernel<<<2 * lc, 256, 0, stream>>>(
            (const u32*)qkv, (const u32*)(qkv + (size_t)1024 * lch),
            (const u32*)(qkv + (size_t)2048 * lch), rpbc,
            (u32*)wsa, c0s[c], bases[c], lc_shift, lch);
        gemm_proj_kernel<<<dim3(4, lc / 128, 2), 256, 0, stream>>>(
            wsa, wproj, bproj, d_out, c0s[c], lc, flag);
    }
}

// Round 5
// 327.725 us; speedup vs baseline: 1.7197x; 1.0331x over previous
//
#include <hip/hip_runtime.h>

typedef unsigned short u16;
typedef unsigned int   u32;
typedef __attribute__((ext_vector_type(8))) short bf16x8;
typedef __attribute__((ext_vector_type(4))) float f32x4;

#define L_SEQ 16384
#define NHEAD 16
#define CDIM  512
#define SCALE 0.17677669529663689f

__device__ __forceinline__ float bf2f(u16 v) {
    union { u32 u; float f; } x; x.u = ((u32)v) << 16; return x.f;
}
__device__ __forceinline__ u16 f2bf(float f) {
    union { u32 u; float f; } x; x.f = f;
    u32 r = x.u + 0x7fff + ((x.u >> 16) & 1);
    return (u16)(r >> 16);
}

// ---- dtype detector: f32 junk low-halves hit bf16-exponent-all-ones w/ p=1/256.
__global__ void detect_dtype_kernel(const u16* __restrict__ x, int* __restrict__ flag) {
    __shared__ int cnt;
    if (threadIdx.x == 0) cnt = 0;
    __syncthreads();
    int c = 0;
    for (int k = 0; k < 32; k++) {
        u16 v = x[2 * (threadIdx.x + 256 * k)];
        if ((v & 0x7F80) == 0x7F80) c++;
    }
    atomicAdd(&cnt, c);
    __syncthreads();
    if (threadIdx.x == 0) *flag = (cnt > 0) ? 1 : 0;
}

// ---- all weights/biases/rpb -> one contiguous bf16 segment (5 sub-ranges)
__global__ __launch_bounds__(256)
void convert_weights_kernel(const void* __restrict__ qkv_w, const void* __restrict__ proj_w,
                            const void* __restrict__ qkv_b, const void* __restrict__ proj_b,
                            const void* __restrict__ rpb, u16* __restrict__ dst,
                            const int* __restrict__ flag) {
    const int f = *flag;
    for (int i = blockIdx.x * 256 + threadIdx.x; i < 1050832; i += gridDim.x * 256) {
        const void* src; int off;
        if (i < 786432)       { src = qkv_w;  off = i; }
        else if (i < 1048576) { src = proj_w; off = i - 786432; }
        else if (i < 1050112) { src = qkv_b;  off = i - 1048576; }
        else if (i < 1050624) { src = proj_b; off = i - 1050112; }
        else                  { src = rpb;    off = i - 1050624; }
        dst[i] = f ? f2bf(((const float*)src)[off]) : ((const u16*)src)[off];
    }
}

// ---- x rows [b*L+base_c, +lch) per b -> xc[(b*lch + r)*512 + col] bf16
__global__ __launch_bounds__(256)
void convert_x_kernel(const void* __restrict__ src, u16* __restrict__ dst,
                      int base_c, int lch, const int* __restrict__ flag) {
    const int f  = *flag;
    const int i0 = (blockIdx.x * 256 + threadIdx.x) * 8;     // [0, 2*lch*512)
    const int r  = i0 >> 9;
    const int b  = (r >= lch) ? 1 : 0;
    const size_t s = (size_t)(b * L_SEQ + base_c + (r - b * lch)) * 512 + (i0 & 511);
    if (f) {
        const float* sf = (const float*)src + s;
        union { u16 o[8]; uint4 v; } pk;
        #pragma unroll
        for (int j = 0; j < 8; j++) pk.o[j] = f2bf(sf[j]);
        *(uint4*)(dst + i0) = pk.v;
    } else {
        *(uint4*)(dst + i0) = *(const uint4*)((const u16*)src + s);
    }
}

// ---- m97-structure GEMM core: 128x128 tile, BK=32, global_load_lds width-16 ----
// A rows AROW0.., W rows N0.. (row-major bf16, K contiguous). C = A @ W^T.
#define GEMM_CORE(A_PTR, W_PTR, KD, AROW0, N0)                                             \
    __shared__ u16 As[128 * 32];                                                           \
    __shared__ u16 Ws[128 * 32];                                                           \
    const int tid  = threadIdx.x;                                                          \
    const int wave = tid >> 6;                                                             \
    const int lane = tid & 63;                                                             \
    const int quad = lane >> 4;                                                            \
    const int r16  = lane & 15;                                                            \
    const int wm   = (wave >> 1) << 6;                                                     \
    const int wn   = (wave & 1) << 6;                                                      \
    f32x4 acc[4][4];                                                                       \
    _Pragma("unroll")                                                                      \
    for (int i = 0; i < 4; i++)                                                            \
        _Pragma("unroll")                                                                  \
        for (int j = 0; j < 4; j++) acc[i][j] = (f32x4){0.f, 0.f, 0.f, 0.f};               \
    const int srow = lane >> 2;                                                            \
    const int scol = (lane & 3) << 3;                                                      \
    u16* asb0 = As + wave * 512;                                                           \
    u16* asb1 = As + 2048 + wave * 512;                                                    \
    u16* wsb0 = Ws + wave * 512;                                                           \
    u16* wsb1 = Ws + 2048 + wave * 512;                                                    \
    const u16* ga = (A_PTR) + (size_t)((AROW0) + wave * 16 + srow) * (KD) + scol;          \
    const u16* gw = (W_PTR) + (size_t)((N0) + wave * 16 + srow) * (KD) + scol;             \
    for (int kt = 0; kt < (KD); kt += 32) {                                                \
        __builtin_amdgcn_global_load_lds(                                                  \
            (const __attribute__((address_space(1))) void*)(ga + kt),                      \
            (__attribute__((address_space(3))) void*)asb0, 16, 0, 0);                      \
        __builtin_amdgcn_global_load_lds(                                                  \
            (const __attribute__((address_space(1))) void*)(ga + (size_t)64 * (KD) + kt),  \
            (__attribute__((address_space(3))) void*)asb1, 16, 0, 0);                      \
        __builtin_amdgcn_global_load_lds(                                                  \
            (const __attribute__((address_space(1))) void*)(gw + kt),                      \
            (__attribute__((address_space(3))) void*)wsb0, 16, 0, 0);                      \
        __builtin_amdgcn_global_load_lds(                                                  \
            (const __attribute__((address_space(1))) void*)(gw + (size_t)64 * (KD) + kt),  \
            (__attribute__((address_space(3))) void*)wsb1, 16, 0, 0);                      \
        __syncthreads();                                                                   \
        bf16x8 af[4], bfr[4];                                                              \
        _Pragma("unroll")                                                                  \
        for (int mi = 0; mi < 4; mi++)                                                     \
            af[mi] = *(const bf16x8*)&As[(wm + mi * 16 + r16) * 32 + quad * 8];            \
        _Pragma("unroll")                                                                  \
        for (int ni = 0; ni < 4; ni++)                                                     \
            bfr[ni] = *(const bf16x8*)&Ws[(wn + ni * 16 + r16) * 32 + quad * 8];           \
        _Pragma("unroll")                                                                  \
        for (int mi = 0; mi < 4; mi++)                                                     \
            _Pragma("unroll")                                                              \
            for (int ni = 0; ni < 4; ni++)                                                 \
                acc[mi][ni] = __builtin_amdgcn_mfma_f32_16x16x32_bf16(                     \
                    af[mi], bfr[ni], acc[mi][ni], 0, 0, 0);                                \
        __syncthreads();                                                                   \
    }

// ---- QKV GEMM: xc[(b*lch+r),512] @ qkv_w^T -> planes [3][b*16+h][lch][32], q*SCALE
// Grid: (m-tiles, 12, 2) with m FASTEST: lin = m + mt*n + 12mt*b; mt ≡ 0 (mod 8)
// -> all n-blocks sharing A-tile m land on XCD m&7 (L2-resident A).
__global__ __launch_bounds__(256)
void gemm_qkv_kernel(const u16* __restrict__ A, const u16* __restrict__ W,
                     const u16* __restrict__ bias, u16* __restrict__ qkv_out, int lch)
{
    const int m0l = blockIdx.x << 7;
    const int n0  = blockIdx.y << 7;
    const int b   = blockIdx.z;
    const size_t plane = (size_t)1024 * lch;       // 2*16*lch*32
    GEMM_CORE(A, W, 512, b * lch + m0l, n0)
    #pragma unroll
    for (int ni = 0; ni < 4; ni++) {
        const int col   = n0 + wn + ni * 16 + r16;
        const int which = col >> 9;
        const int rem   = col & 511;
        const int h     = rem >> 5;
        const int d     = rem & 31;
        const float bv  = bf2f(bias[col]);
        const float scl = (which == 0) ? SCALE : 1.0f;
        u16* outb = qkv_out + (size_t)which * plane;
        #pragma unroll
        for (int mi = 0; mi < 4; mi++) {
            #pragma unroll
            for (int r = 0; r < 4; r++) {
                const int rrel = m0l + wm + mi * 16 + quad * 4 + r;
                outb[((size_t)(b * NHEAD + h) * lch + rrel) * 32 + d] =
                    f2bf((acc[mi][ni][r] + bv) * scl);
            }
        }
    }
}

// ---- attention: 16 lanes per (b,h,l), each lane owns a bf16 pair (d2 = d/2)
__global__ __launch_bounds__(256)
void attn_kernel(const u32* __restrict__ q, const u32* __restrict__ k,
                 const u32* __restrict__ v, const u16* __restrict__ rpb,
                 u32* __restrict__ outa, int c0, int base_c, int lc_shift, int lch)
{
    const int grp = blockIdx.x * 16 + (threadIdx.x >> 4);
    const int d2  = threadIdx.x & 15;
    const int lc_mask = (1 << lc_shift) - 1;
    const int lr  = grp & lc_mask;
    const int bh  = grp >> lc_shift;                // b*16 + h
    const int h   = bh & 15;
    const int l   = c0 + lr;
    const size_t base = (size_t)bh * lch * 16;      // in u32 units

    const u32 qp = q[base + (size_t)(l - base_c) * 16 + d2];
    const float qlo = bf2f((u16)qp), qhi = bf2f((u16)(qp >> 16));
    int ni = l - 3;
    if (ni < 0) ni = 0;
    if (ni > L_SEQ - 7) ni = L_SEQ - 7;
    const int rn = ni - base_c;

    float logit[7];
    #pragma unroll
    for (int j = 0; j < 7; j++) {
        const u32 kp = k[base + (size_t)(rn + j) * 16 + d2];
        float p = qlo * bf2f((u16)kp) + qhi * bf2f((u16)(kp >> 16));
        #pragma unroll
        for (int m = 8; m >= 1; m >>= 1) p += __shfl_xor(p, m, 64);
        logit[j] = p + bf2f(rpb[h * 13 + (ni + j - l + 6)]);
    }
    float mx = logit[0];
    #pragma unroll
    for (int j = 1; j < 7; j++) mx = fmaxf(mx, logit[j]);
    float s = 0.f, w[7];
    #pragma unroll
    for (int j = 0; j < 7; j++) { w[j] = __expf(logit[j] - mx); s += w[j]; }
    const float inv = 1.0f / s;
    float olo = 0.f, ohi = 0.f;
    #pragma unroll
    for (int j = 0; j < 7; j++) {
        const u32 vp = v[base + (size_t)(rn + j) * 16 + d2];
        olo += w[j] * bf2f((u16)vp);
        ohi += w[j] * bf2f((u16)(vp >> 16));
    }
    const u32 pk = (u32)f2bf(olo * inv) | ((u32)f2bf(ohi * inv) << 16);
    outa[((size_t)(((bh >> 4) << lc_shift) + lr)) * 256 + h * 16 + d2] = pk;
}

// ---- proj GEMM: wsa[(b*lc+lr),512] @ proj_w^T -> out rows b*L + c0 + lr
// Grid: (m-tiles, 4, 2), m fastest — same XCD-locality swizzle as qkv.
__global__ __launch_bounds__(256)
void gemm_proj_kernel(const u16* __restrict__ A, const u16* __restrict__ W,
                      const u16* __restrict__ bias, void* __restrict__ out,
                      int c0, int lc, const int* __restrict__ flag)
{
    const int m0l = blockIdx.x << 7;
    const int n0  = blockIdx.y << 7;
    const int b   = blockIdx.z;
    GEMM_CORE(A, W, 512, b * lc + m0l, n0)
    const int f = *flag;
    #pragma unroll
    for (int ni = 0; ni < 4; ni++) {
        const int col  = n0 + wn + ni * 16 + r16;
        const float bv = bf2f(bias[col]);
        #pragma unroll
        for (int mi = 0; mi < 4; mi++) {
            #pragma unroll
            for (int r = 0; r < 4; r++) {
                const int lr = m0l + wm + mi * 16 + quad * 4 + r;
                const size_t idx = (size_t)(b * L_SEQ + c0 + lr) * CDIM + col;
                const float val = acc[mi][ni][r] + bv;
                if (f) ((float*)out)[idx] = val;
                else   ((u16*)out)[idx]   = f2bf(val);
            }
        }
    }
}

extern "C" void kernel_launch(void* const* d_in, const int* in_sizes, int n_in,
                              void* d_out, int out_size, void* d_ws, size_t ws_size,
                              hipStream_t stream) {
    const void* x      = d_in[0];
    const void* qkv_w  = d_in[1];
    const void* qkv_b  = d_in[2];
    const void* rpb    = d_in[3];
    const void* proj_w = d_in[4];
    const void* proj_b = d_in[5];

    // ---- chunk config chosen by ws_size (constant across calls -> graph-safe)
    int nchunk, lch, lc, lc_shift;
    static const int c0sA[1] = {0},                 basesA[1] = {0};
    static const int c0sB[2] = {0, 8192},           basesB[2] = {0, 8064};
    static const int c0sC[8] = {0, 2048, 4096, 6144, 8192, 10240, 12288, 14336};
    static const int basesC[8] = {0, 1984, 4032, 6080, 8128, 10176, 12224, 14208};
    const int* c0s; const int* bases;
    if (ws_size >= (size_t)2 * (16 + 1050880 + (size_t)4096 * 16384 + 1024 * 16384)) {
        nchunk = 1; lch = 16384; lc = 16384; lc_shift = 14; c0s = c0sA; bases = basesA;
    } else if (ws_size >= (size_t)2 * (16 + 1050880 + (size_t)4096 * 8320 + 1024 * 8192)) {
        nchunk = 2; lch = 8320;  lc = 8192;  lc_shift = 13; c0s = c0sB; bases = basesB;
    } else {
        nchunk = 8; lch = 2176;  lc = 2048;  lc_shift = 11; c0s = c0sC; bases = basesC;
    }

    u16* ws    = (u16*)d_ws;
    int* flag  = (int*)ws;                           // 16 u16
    u16* wseg  = ws + 16;                            // wqkv|wproj|bqkv|bproj|rpbc
    u16* wqkv  = wseg;
    u16* wproj = wseg + 786432;
    u16* bqkv  = wseg + 1048576;
    u16* bproj = wseg + 1050112;
    u16* rpbc  = wseg + 1050624;
    u16* xc    = ws + 16 + 1050880;                  // 2*lch*512
    u16* qkv   = xc + (size_t)1024 * lch;            // 3 planes of 1024*lch
    u16* wsa   = qkv + (size_t)3072 * lch;           // 2*lc*512

    detect_dtype_kernel<<<1, 256, 0, stream>>>((const u16*)x, flag);
    convert_weights_kernel<<<2048, 256, 0, stream>>>(qkv_w, proj_w, qkv_b, proj_b,
                                                     rpb, wseg, flag);

    for (int c = 0; c < nchunk; c++) {
        convert_x_kernel<<<lch / 2, 256, 0, stream>>>(x, xc, bases[c], lch, flag);
        gemm_qkv_kernel<<<dim3(lch / 128, 12, 2), 256, 0, stream>>>(
            xc, wqkv, bqkv, qkv, lch);
        attn_kernel<<<2 * lc, 256, 0, stream>>>(
            (const u32*)qkv, (const u32*)(qkv + (size_t)1024 * lch),
            (const u32*)(qkv + (size_t)2048 * lch), rpbc,
            (u32*)wsa, c0s[c], bases[c], lc_shift, lch);
        gemm_proj_kernel<<<dim3(lc / 128, 4, 2), 256, 0, stream>>>(
            wsa, wproj, bproj, d_out, c0s[c], lc, flag);
    }
}

// Round 6
// 289.781 us; speedup vs baseline: 1.9448x; 1.1309x over previous
//
#include <hip/hip_runtime.h>

typedef unsigned short u16;
typedef unsigned int   u32;
typedef __attribute__((ext_vector_type(8))) short bf16x8;
typedef __attribute__((ext_vector_type(4))) float f32x4;

#define L_SEQ 16384
#define NHEAD 16
#define CDIM  512
#define SCALE 0.17677669529663689f

__device__ __forceinline__ float bf2f(u16 v) {
    union { u32 u; float f; } x; x.u = ((u32)v) << 16; return x.f;
}
__device__ __forceinline__ u16 f2bf(float f) {
    union { u32 u; float f; } x; x.f = f;
    u32 r = x.u + 0x7fff + ((x.u >> 16) & 1);
    return (u16)(r >> 16);
}

// ---- dtype detector: f32 junk low-halves hit bf16-exponent-all-ones w/ p=1/256.
__global__ void detect_dtype_kernel(const u16* __restrict__ x, int* __restrict__ flag) {
    __shared__ int cnt;
    if (threadIdx.x == 0) cnt = 0;
    __syncthreads();
    int c = 0;
    for (int k = 0; k < 32; k++) {
        u16 v = x[2 * (threadIdx.x + 256 * k)];
        if ((v & 0x7F80) == 0x7F80) c++;
    }
    atomicAdd(&cnt, c);
    __syncthreads();
    if (threadIdx.x == 0) *flag = (cnt > 0) ? 1 : 0;
}

// ---- all weights/biases/rpb -> one contiguous bf16 segment (5 sub-ranges)
__global__ __launch_bounds__(256)
void convert_weights_kernel(const void* __restrict__ qkv_w, const void* __restrict__ proj_w,
                            const void* __restrict__ qkv_b, const void* __restrict__ proj_b,
                            const void* __restrict__ rpb, u16* __restrict__ dst,
                            const int* __restrict__ flag) {
    const int f = *flag;
    for (int i = blockIdx.x * 256 + threadIdx.x; i < 1050832; i += gridDim.x * 256) {
        const void* src; int off;
        if (i < 786432)       { src = qkv_w;  off = i; }
        else if (i < 1048576) { src = proj_w; off = i - 786432; }
        else if (i < 1050112) { src = qkv_b;  off = i - 1048576; }
        else if (i < 1050624) { src = proj_b; off = i - 1050112; }
        else                  { src = rpb;    off = i - 1050624; }
        dst[i] = f ? f2bf(((const float*)src)[off]) : ((const u16*)src)[off];
    }
}

// ---- x rows [b*L+base_c, +lch) per b -> xc[(b*lch + r)*512 + col] bf16
__global__ __launch_bounds__(256)
void convert_x_kernel(const void* __restrict__ src, u16* __restrict__ dst,
                      int base_c, int lch, const int* __restrict__ flag) {
    const int f  = *flag;
    const int i0 = (blockIdx.x * 256 + threadIdx.x) * 8;     // [0, 2*lch*512)
    const int r  = i0 >> 9;
    const int b  = (r >= lch) ? 1 : 0;
    const size_t s = (size_t)(b * L_SEQ + base_c + (r - b * lch)) * 512 + (i0 & 511);
    if (f) {
        const float* sf = (const float*)src + s;
        union { u16 o[8]; uint4 v; } pk;
        #pragma unroll
        for (int j = 0; j < 8; j++) pk.o[j] = f2bf(sf[j]);
        *(uint4*)(dst + i0) = pk.v;
    } else {
        *(uint4*)(dst + i0) = *(const uint4*)((const u16*)src + s);
    }
}

// ---- GEMM core: 128x128 tile, BK=64, XOR-swizzled LDS, global_load_lds w16 ----
// LDS phys layout: [row][64], 16B chunk at phys index pc holds logical chunk
// lc = pc ^ (row&7). Staging: lane fetches global chunk (lane&7)^(lane>>3) so the
// forced dest (base+lane*16) lands it at the right phys slot. ds_read_b128 of
// fragment (row=..+r16, chunk ks*4+quad) reads phys ((ks*4+quad)^(r16&7)) ->
// 8 distinct bank groups across r16 (2-way alias = free).
#define GEMM_CORE(A_PTR, W_PTR, KD, AROW0, N0)                                             \
    __shared__ u16 As[128 * 64];                                                           \
    __shared__ u16 Ws[128 * 64];                                                           \
    const int tid  = threadIdx.x;                                                          \
    const int wave = tid >> 6;                                                             \
    const int lane = tid & 63;                                                             \
    const int quad = lane >> 4;                                                            \
    const int r16  = lane & 15;                                                            \
    const int wm   = (wave >> 1) << 6;                                                     \
    const int wn   = (wave & 1) << 6;                                                      \
    f32x4 acc[4][4];                                                                       \
    _Pragma("unroll")                                                                      \
    for (int i = 0; i < 4; i++)                                                            \
        _Pragma("unroll")                                                                  \
        for (int j = 0; j < 4; j++) acc[i][j] = (f32x4){0.f, 0.f, 0.f, 0.f};               \
    const int lr8 = lane >> 3;                                                             \
    const int swc = ((lane & 7) ^ lr8) << 3;       /* swizzled source col (u16) */         \
    const u16* ga = (A_PTR) + (size_t)((AROW0) + wave * 8 + lr8) * (KD) + swc;             \
    const u16* gw = (W_PTR) + (size_t)((N0) + wave * 8 + lr8) * (KD) + swc;                \
    u16* asb = As + wave * 512;                    /* wave*8 rows * 64 */                  \
    u16* wsb = Ws + wave * 512;                                                            \
    for (int kt = 0; kt < (KD); kt += 64) {                                                \
        _Pragma("unroll")                                                                  \
        for (int t = 0; t < 4; t++) {                                                      \
            __builtin_amdgcn_global_load_lds(                                              \
                (const __attribute__((address_space(1))) void*)(ga + kt + (size_t)(t * 32) * (KD)), \
                (__attribute__((address_space(3))) void*)(asb + t * 2048), 16, 0, 0);      \
            __builtin_amdgcn_global_load_lds(                                              \
                (const __attribute__((address_space(1))) void*)(gw + kt + (size_t)(t * 32) * (KD)), \
                (__attribute__((address_space(3))) void*)(wsb + t * 2048), 16, 0, 0);      \
        }                                                                                  \
        __syncthreads();                                                                   \
        _Pragma("unroll")                                                                  \
        for (int ks = 0; ks < 2; ks++) {                                                   \
            bf16x8 af[4], bfr[4];                                                          \
            _Pragma("unroll")                                                              \
            for (int mi = 0; mi < 4; mi++)                                                 \
                af[mi] = *(const bf16x8*)&As[(wm + mi * 16 + r16) * 64 +                   \
                                             (((ks * 4 + quad) ^ (r16 & 7)) << 3)];        \
            _Pragma("unroll")                                                              \
            for (int ni = 0; ni < 4; ni++)                                                 \
                bfr[ni] = *(const bf16x8*)&Ws[(wn + ni * 16 + r16) * 64 +                  \
                                              (((ks * 4 + quad) ^ (r16 & 7)) << 3)];       \
            _Pragma("unroll")                                                              \
            for (int mi = 0; mi < 4; mi++)                                                 \
                _Pragma("unroll")                                                          \
                for (int ni = 0; ni < 4; ni++)                                             \
                    acc[mi][ni] = __builtin_amdgcn_mfma_f32_16x16x32_bf16(                 \
                        af[mi], bfr[ni], acc[mi][ni], 0, 0, 0);                            \
        }                                                                                  \
        __syncthreads();                                                                   \
    }

// ---- QKV GEMM: xc[(b*lch+r),512] @ qkv_w^T -> planes [3][b*16+h][lch][32], q*SCALE
// Grid (m-tiles, 12, 2), m fastest; m-tiles ≡ 0 (mod 8) -> A-tile XCD-resident.
__global__ __launch_bounds__(256)
void gemm_qkv_kernel(const u16* __restrict__ A, const u16* __restrict__ W,
                     const u16* __restrict__ bias, u16* __restrict__ qkv_out, int lch)
{
    const int m0l = blockIdx.x << 7;
    const int n0  = blockIdx.y << 7;
    const int b   = blockIdx.z;
    const size_t plane = (size_t)1024 * lch;       // 2*16*lch*32
    GEMM_CORE(A, W, 512, b * lch + m0l, n0)
    #pragma unroll
    for (int ni = 0; ni < 4; ni++) {
        const int col   = n0 + wn + ni * 16 + r16;
        const int which = col >> 9;
        const int rem   = col & 511;
        const int h     = rem >> 5;
        const int d     = rem & 31;
        const float bv  = bf2f(bias[col]);
        const float scl = (which == 0) ? SCALE : 1.0f;
        u16* outb = qkv_out + (size_t)which * plane;
        #pragma unroll
        for (int mi = 0; mi < 4; mi++) {
            #pragma unroll
            for (int r = 0; r < 4; r++) {
                const int rrel = m0l + wm + mi * 16 + quad * 4 + r;
                outb[((size_t)(b * NHEAD + h) * lch + rrel) * 32 + d] =
                    f2bf((acc[mi][ni][r] + bv) * scl);
            }
        }
    }
}

// ---- attention: 4 lanes per (b,h,l); each lane owns 8 bf16 (one uint4)
__global__ __launch_bounds__(256)
void attn_kernel(const uint4* __restrict__ q, const uint4* __restrict__ k,
                 const uint4* __restrict__ v, const u16* __restrict__ rpb,
                 uint4* __restrict__ outa, int c0, int base_c, int lc_shift, int lch)
{
    const int grp = blockIdx.x * 64 + (threadIdx.x >> 2);
    const int d4  = threadIdx.x & 3;
    const int lr  = grp & ((1 << lc_shift) - 1);
    const int bh  = grp >> lc_shift;                // b*16 + h
    const int h   = bh & 15;
    const int l   = c0 + lr;
    const size_t base = (size_t)bh * lch * 4;       // uint4 per row = 4

    const uint4 qp = q[base + (size_t)(l - base_c) * 4 + d4];
    float qf[8];
    qf[0] = bf2f((u16)qp.x); qf[1] = bf2f((u16)(qp.x >> 16));
    qf[2] = bf2f((u16)qp.y); qf[3] = bf2f((u16)(qp.y >> 16));
    qf[4] = bf2f((u16)qp.z); qf[5] = bf2f((u16)(qp.z >> 16));
    qf[6] = bf2f((u16)qp.w); qf[7] = bf2f((u16)(qp.w >> 16));

    int ni = l - 3;
    if (ni < 0) ni = 0;
    if (ni > L_SEQ - 7) ni = L_SEQ - 7;
    const int rn = ni - base_c;

    float logit[7];
    #pragma unroll
    for (int j = 0; j < 7; j++) {
        const uint4 kp = k[base + (size_t)(rn + j) * 4 + d4];
        float p;
        p  = qf[0] * bf2f((u16)kp.x) + qf[1] * bf2f((u16)(kp.x >> 16));
        p += qf[2] * bf2f((u16)kp.y) + qf[3] * bf2f((u16)(kp.y >> 16));
        p += qf[4] * bf2f((u16)kp.z) + qf[5] * bf2f((u16)(kp.z >> 16));
        p += qf[6] * bf2f((u16)kp.w) + qf[7] * bf2f((u16)(kp.w >> 16));
        p += __shfl_xor(p, 1, 64);
        p += __shfl_xor(p, 2, 64);
        logit[j] = p + bf2f(rpb[h * 13 + (ni + j - l + 6)]);
    }
    float mx = logit[0];
    #pragma unroll
    for (int j = 1; j < 7; j++) mx = fmaxf(mx, logit[j]);
    float s = 0.f, w[7];
    #pragma unroll
    for (int j = 0; j < 7; j++) { w[j] = __expf(logit[j] - mx); s += w[j]; }
    const float inv = 1.0f / s;
    float o[8] = {0.f, 0.f, 0.f, 0.f, 0.f, 0.f, 0.f, 0.f};
    #pragma unroll
    for (int j = 0; j < 7; j++) {
        const uint4 vp = v[base + (size_t)(rn + j) * 4 + d4];
        o[0] += w[j] * bf2f((u16)vp.x); o[1] += w[j] * bf2f((u16)(vp.x >> 16));
        o[2] += w[j] * bf2f((u16)vp.y); o[3] += w[j] * bf2f((u16)(vp.y >> 16));
        o[4] += w[j] * bf2f((u16)vp.z); o[5] += w[j] * bf2f((u16)(vp.z >> 16));
        o[6] += w[j] * bf2f((u16)vp.w); o[7] += w[j] * bf2f((u16)(vp.w >> 16));
    }
    uint4 pk;
    pk.x = (u32)f2bf(o[0] * inv) | ((u32)f2bf(o[1] * inv) << 16);
    pk.y = (u32)f2bf(o[2] * inv) | ((u32)f2bf(o[3] * inv) << 16);
    pk.z = (u32)f2bf(o[4] * inv) | ((u32)f2bf(o[5] * inv) << 16);
    pk.w = (u32)f2bf(o[6] * inv) | ((u32)f2bf(o[7] * inv) << 16);
    outa[((size_t)(((bh >> 4) << lc_shift) + lr)) * 64 + h * 4 + d4] = pk;
}

// ---- proj GEMM: wsa[(b*lc+lr),512] @ proj_w^T -> out rows b*L + c0 + lr
__global__ __launch_bounds__(256)
void gemm_proj_kernel(const u16* __restrict__ A, const u16* __restrict__ W,
                      const u16* __restrict__ bias, void* __restrict__ out,
                      int c0, int lc, const int* __restrict__ flag)
{
    const int m0l = blockIdx.x << 7;
    const int n0  = blockIdx.y << 7;
    const int b   = blockIdx.z;
    GEMM_CORE(A, W, 512, b * lc + m0l, n0)
    const int f = *flag;
    #pragma unroll
    for (int ni = 0; ni < 4; ni++) {
        const int col  = n0 + wn + ni * 16 + r16;
        const float bv = bf2f(bias[col]);
        #pragma unroll
        for (int mi = 0; mi < 4; mi++) {
            #pragma unroll
            for (int r = 0; r < 4; r++) {
                const int lr = m0l + wm + mi * 16 + quad * 4 + r;
                const size_t idx = (size_t)(b * L_SEQ + c0 + lr) * CDIM + col;
                const float val = acc[mi][ni][r] + bv;
                if (f) ((float*)out)[idx] = val;
                else   ((u16*)out)[idx]   = f2bf(val);
            }
        }
    }
}

extern "C" void kernel_launch(void* const* d_in, const int* in_sizes, int n_in,
                              void* d_out, int out_size, void* d_ws, size_t ws_size,
                              hipStream_t stream) {
    const void* x      = d_in[0];
    const void* qkv_w  = d_in[1];
    const void* qkv_b  = d_in[2];
    const void* rpb    = d_in[3];
    const void* proj_w = d_in[4];
    const void* proj_b = d_in[5];

    // ---- chunk config chosen by ws_size (constant across calls -> graph-safe)
    int nchunk, lch, lc, lc_shift;
    static const int c0sA[1] = {0},                 basesA[1] = {0};
    static const int c0sB[2] = {0, 8192},           basesB[2] = {0, 8064};
    static const int c0sC[8] = {0, 2048, 4096, 6144, 8192, 10240, 12288, 14336};
    static const int basesC[8] = {0, 1984, 4032, 6080, 8128, 10176, 12224, 14208};
    const int* c0s; const int* bases;
    if (ws_size >= (size_t)2 * (16 + 1050880 + (size_t)4096 * 16384 + 1024 * 16384)) {
        nchunk = 1; lch = 16384; lc = 16384; lc_shift = 14; c0s = c0sA; bases = basesA;
    } else if (ws_size >= (size_t)2 * (16 + 1050880 + (size_t)4096 * 8320 + 1024 * 8192)) {
        nchunk = 2; lch = 8320;  lc = 8192;  lc_shift = 13; c0s = c0sB; bases = basesB;
    } else {
        nchunk = 8; lch = 2176;  lc = 2048;  lc_shift = 11; c0s = c0sC; bases = basesC;
    }

    u16* ws    = (u16*)d_ws;
    int* flag  = (int*)ws;                           // 16 u16
    u16* wseg  = ws + 16;                            // wqkv|wproj|bqkv|bproj|rpbc
    u16* wqkv  = wseg;
    u16* wproj = wseg + 786432;
    u16* bqkv  = wseg + 1048576;
    u16* bproj = wseg + 1050112;
    u16* rpbc  = wseg + 1050624;
    u16* xc    = ws + 16 + 1050880;                  // 2*lch*512
    u16* qkv   = xc + (size_t)1024 * lch;            // 3 planes of 1024*lch
    u16* wsa   = qkv + (size_t)3072 * lch;           // 2*lc*512

    detect_dtype_kernel<<<1, 256, 0, stream>>>((const u16*)x, flag);
    convert_weights_kernel<<<2048, 256, 0, stream>>>(qkv_w, proj_w, qkv_b, proj_b,
                                                     rpb, wseg, flag);

    for (int c = 0; c < nchunk; c++) {
        convert_x_kernel<<<lch / 2, 256, 0, stream>>>(x, xc, bases[c], lch, flag);
        gemm_qkv_kernel<<<dim3(lch / 128, 12, 2), 256, 0, stream>>>(
            xc, wqkv, bqkv, qkv, lch);
        attn_kernel<<<lc / 2, 256, 0, stream>>>(
            (const uint4*)qkv, (const uint4*)(qkv + (size_t)1024 * lch),
            (const uint4*)(qkv + (size_t)2048 * lch), rpbc,
            (uint4*)wsa, c0s[c], bases[c], lc_shift, lch);
        gemm_proj_kernel<<<dim3(lc / 128, 4, 2), 256, 0, stream>>>(
            wsa, wproj, bproj, d_out, c0s[c], lc, flag);
    }
}